// Round 17
// baseline (419.725 us; speedup 1.0000x reference)
//
#include <hip/hip_runtime.h>
#include <hip/hip_fp16.h>

// Problem constants (match reference)
#define NN   100000              // nodes
#define NE   1600000             // edges before self loops
#define ET   (NE + NN)           // edges incl. self loops
#define INF_ 128                 // input features
#define HID  64                  // hidden
#define NG   256                 // graphs
#define BN_EPS 1e-5f
#define NEG  0.2f

// bucket partition geometry (CSR fill)
#define BSPAN_LOG 8
#define BSPAN     (1 << BSPAN_LOG)                 // 256 dst nodes per bucket
#define NBUK      ((NN + BSPAN - 1) / BSPAN)       // 391
#define BUKCAP    5120                             // >= mu+12sigma of bucket load
#define P1_EPT    16
#define P1_CHUNK  (256 * P1_EPT)                   // 4096 edges per block
#define P1_GRID   ((ET + P1_CHUNK - 1) / P1_CHUNK) // 416
#define GEMM_GRID (NN / 16)                        // 6250

__device__ __forceinline__ float lrelu(float v) { return v > 0.f ? v : NEG * v; }

__device__ __forceinline__ float readlane_f(float v, int l) {
  return __int_as_float(__builtin_amdgcn_readlane(__float_as_int(v), l));
}

// ---------------- unified init ----------------
__global__ __launch_bounds__(256) void init_k(
    int* __restrict__ bukcur, int* __restrict__ rowptr,
    float* __restrict__ fsum1, float* __restrict__ fsq1,
    float* __restrict__ fsum2, float* __restrict__ fsq2,
    float* __restrict__ pooled, float* __restrict__ cnt) {
  int i = blockIdx.x * 256 + threadIdx.x;
  if (i == 0) rowptr[NN] = ET;
  if (i < NBUK) bukcur[i] = i * BUKCAP;
  if (i < HID) { fsum1[i] = 0.f; fsq1[i] = 0.f; fsum2[i] = 0.f; fsq2[i] = 0.f; }
  if (i < NG * HID) pooled[i] = 0.f;
  if (i < NG) cnt[i] = 0.f;
}

// ---------------- part1 core (bucket partition) ----------------
__device__ __forceinline__ void part1_core(
    float* smem, const int* __restrict__ ei, int* __restrict__ bukcur,
    int2* __restrict__ stage, int blk) {
  int* hist = (int*)smem;
  int* base = hist + NBUK;
  int t = threadIdx.x;
  for (int b = t; b < NBUK; b += 256) hist[b] = 0;
  __syncthreads();
  int chunk = blk * P1_CHUNK;
  int myb[P1_EPT], myr[P1_EPT], mys[P1_EPT], myd[P1_EPT];
#pragma unroll
  for (int it = 0; it < P1_EPT; ++it) {
    int i = chunk + it * 256 + t;
    bool v = i < ET;
    int src = 0, dst = 0;
    if (v) {
      src = i < NE ? ei[i] : i - NE;
      dst = i < NE ? ei[NE + i] : i - NE;
    }
    myb[it] = v ? (dst >> BSPAN_LOG) : -1;
    mys[it] = src;
    myd[it] = dst;
    myr[it] = v ? atomicAdd(&hist[dst >> BSPAN_LOG], 1) : 0;
  }
  __syncthreads();
  for (int b = t; b < NBUK; b += 256)
    base[b] = hist[b] ? atomicAdd(&bukcur[b], hist[b]) : 0;
  __syncthreads();
#pragma unroll
  for (int it = 0; it < P1_EPT; ++it)
    if (myb[it] >= 0)
      stage[base[myb[it]] + myr[it]] = make_int2(mys[it], myd[it]);
}

// ---------------- gemm core (v4 + fp16 h) ----------------
// h = (x*bnA+bnC) @ W (fp16 out); alpha_s/alpha_d from FP32 accumulators.
// W in LDS [k][f] (lane stride-1, conflict-free). x rows WAVE-UNIFORM via
// readfirstlane -> scalar loads. NOTE R5/R7/R8-R10 lessons in history.
template <int K, bool STATS>
__device__ __forceinline__ void gemm_core(
    float* Wl, float* cvec, float* scl, float* shf, int blk,
    const float* __restrict__ x,
    const float* __restrict__ fsum, const float* __restrict__ fsq,
    const float* __restrict__ bng, const float* __restrict__ bnb,
    const float* __restrict__ W,
    const float* __restrict__ a_s, const float* __restrict__ a_d,
    __half* __restrict__ h, float* __restrict__ sv_out, float* __restrict__ dv_out) {
  int tid = threadIdx.x;
  if (tid < HID) {
    cvec[tid] = 0.f;
    if (STATS) {
      float m = fsum[tid] * (1.0f / NN);
      float v = fsq[tid] * (1.0f / NN) - m * m;
      float a = bng[tid] * rsqrtf(v + BN_EPS);
      scl[tid] = a;
      shf[tid] = bnb[tid] - m * a;
    }
  }
  __syncthreads();
  if (STATS) {
    float clocal = 0.f;
    for (int i = tid; i < K * HID; i += 256) {
      int k = i >> 6;
      float w = W[i];
      clocal += shf[k] * w;
      Wl[i] = w * scl[k];
    }
    atomicAdd(&cvec[tid & 63], clocal);
  } else {
    for (int i = tid; i < K * HID; i += 256) Wl[i] = W[i];
  }
  __syncthreads();

  int lane = tid & 63;
  int wid = tid >> 6;
  int row0 = blk * 16 + wid * 4;
  int ur = __builtin_amdgcn_readfirstlane(row0);
  const float* xr0 = x + (size_t)ur * K;   // uniform -> scalar loads
  const float* xr1 = xr0 + K;
  const float* xr2 = xr0 + 2 * K;
  const float* xr3 = xr0 + 3 * K;
  float cv = cvec[lane];
  float a0 = cv, a1 = cv, a2 = cv, a3 = cv;
#pragma unroll 4
  for (int k = 0; k < K; k += 4) {
    float4 v0 = *(const float4*)(xr0 + k);
    float4 v1 = *(const float4*)(xr1 + k);
    float4 v2 = *(const float4*)(xr2 + k);
    float4 v3 = *(const float4*)(xr3 + k);
    float w0 = Wl[(k + 0) * HID + lane];
    float w1 = Wl[(k + 1) * HID + lane];
    float w2 = Wl[(k + 2) * HID + lane];
    float w3 = Wl[(k + 3) * HID + lane];
    a0 = fmaf(v0.x, w0, a0); a0 = fmaf(v0.y, w1, a0);
    a0 = fmaf(v0.z, w2, a0); a0 = fmaf(v0.w, w3, a0);
    a1 = fmaf(v1.x, w0, a1); a1 = fmaf(v1.y, w1, a1);
    a1 = fmaf(v1.z, w2, a1); a1 = fmaf(v1.w, w3, a1);
    a2 = fmaf(v2.x, w0, a2); a2 = fmaf(v2.y, w1, a2);
    a2 = fmaf(v2.z, w2, a2); a2 = fmaf(v2.w, w3, a2);
    a3 = fmaf(v3.x, w0, a3); a3 = fmaf(v3.y, w1, a3);
    a3 = fmaf(v3.z, w2, a3); a3 = fmaf(v3.w, w3, a3);
  }

  float asl = a_s[lane], adl = a_d[lane];
  h[(size_t)(row0 + 0) * HID + lane] = __float2half(a0);
  h[(size_t)(row0 + 1) * HID + lane] = __float2half(a1);
  h[(size_t)(row0 + 2) * HID + lane] = __float2half(a2);
  h[(size_t)(row0 + 3) * HID + lane] = __float2half(a3);
  float s0 = a0 * asl, d0 = a0 * adl;
  float s1 = a1 * asl, d1 = a1 * adl;
  float s2 = a2 * asl, d2 = a2 * adl;
  float s3 = a3 * asl, d3 = a3 * adl;
  for (int o = 32; o; o >>= 1) {
    s0 += __shfl_xor(s0, o); d0 += __shfl_xor(d0, o);
    s1 += __shfl_xor(s1, o); d1 += __shfl_xor(d1, o);
    s2 += __shfl_xor(s2, o); d2 += __shfl_xor(d2, o);
    s3 += __shfl_xor(s3, o); d3 += __shfl_xor(d3, o);
  }
  if (lane == 0) {
    sv_out[row0 + 0] = s0; dv_out[row0 + 0] = d0;
    sv_out[row0 + 1] = s1; dv_out[row0 + 1] = d1;
    sv_out[row0 + 2] = s2; dv_out[row0 + 2] = d2;
    sv_out[row0 + 3] = s3; dv_out[row0 + 3] = d3;
  }
}

// fused: blocks [0, P1_GRID) run the bucket partition; the rest run gemm1.
// Independent inputs (ei vs x/W1) -> memory-heavy and VALU-heavy work
// co-schedule instead of running serially.
__global__ __launch_bounds__(256) void p1_gemm1_k(
    const int* __restrict__ ei, int* __restrict__ bukcur, int2* __restrict__ stage,
    const float* __restrict__ x, const float* __restrict__ W1,
    const float* __restrict__ as1, const float* __restrict__ ad1,
    __half* __restrict__ h, float* __restrict__ sv, float* __restrict__ dv) {
  extern __shared__ float smem[];
  if (blockIdx.x < P1_GRID) {
    part1_core(smem, ei, bukcur, stage, blockIdx.x);
  } else {
    float* Wl = smem;
    float* cvec = Wl + INF_ * HID;
    gemm_core<INF_, false>(Wl, cvec, nullptr, nullptr, (int)blockIdx.x - P1_GRID,
                           x, nullptr, nullptr, nullptr, nullptr, W1, as1, ad1,
                           h, sv, dv);
  }
}

// standalone gemm2 (STATS=true: BN1 affine inline)
template <int K, bool STATS>
__global__ __launch_bounds__(256) void gemm_att(
    const float* __restrict__ x,
    const float* __restrict__ fsum, const float* __restrict__ fsq,
    const float* __restrict__ bng, const float* __restrict__ bnb,
    const float* __restrict__ W,
    const float* __restrict__ a_s, const float* __restrict__ a_d,
    __half* __restrict__ h, float* __restrict__ sv_out, float* __restrict__ dv_out) {
  __shared__ float Wl[K * HID];
  __shared__ float cvec[HID];
  __shared__ float scl[HID], shf[HID];
  gemm_core<K, STATS>(Wl, cvec, scl, shf, blockIdx.x, x, fsum, fsq, bng, bnb,
                      W, a_s, a_d, h, sv_out, dv_out);
}

// phase 2: one block per bucket; computes its own bucket base from bukcur
// (391 L2-hot ints; bukscan_k deleted). Pass A: per-dst LDS histogram from
// the bucket's stage window. Pass B: LDS scan -> rowptr. Pass C: scatter.
__global__ __launch_bounds__(256) void part2_k(const int2* __restrict__ stage,
                                               const int* __restrict__ bukcur,
                                               int* __restrict__ rowptr,
                                               int* __restrict__ esrc) {
  __shared__ int lcnt[BSPAN];
  __shared__ int lscan[BSPAN];
  int b = blockIdx.x;
  int node0 = b << BSPAN_LOG;
  int t = threadIdx.x;
  // inline bucket base: sum of counts of buckets < b
  int partial = 0;
  for (int i = t; i < b; i += 256) partial += bukcur[i] - i * BUKCAP;
  lscan[t] = partial;
  __syncthreads();
  for (int off = 128; off; off >>= 1) {
    if (t < off) lscan[t] += lscan[t + off];
    __syncthreads();
  }
  int bbase = lscan[0];
  lcnt[t] = 0;
  __syncthreads();
  int s = b * BUKCAP, e = bukcur[b];
  for (int i = s + t; i < e; i += 256)
    atomicAdd(&lcnt[stage[i].y - node0], 1);
  __syncthreads();
  int v = lcnt[t];
  lscan[t] = v;
  __syncthreads();
  for (int off = 1; off < 256; off <<= 1) {
    int add = (t >= off) ? lscan[t - off] : 0;
    __syncthreads();
    lscan[t] += add;
    __syncthreads();
  }
  int excl = bbase + lscan[t] - v;
  if (node0 + t < NN) rowptr[node0 + t] = excl;
  lcnt[t] = excl;
  __syncthreads();
  for (int i = s + t; i < e; i += 256) {
    int2 p = stage[i];
    int pos = atomicAdd(&lcnt[p.y - node0], 1);
    esrc[pos] = p.x;
  }
}

// ---------------- half-wave node processing (deg <= 32) ----------------
__device__ __forceinline__ float2 gat_node_half(
    int node, int start, int deg, const int* __restrict__ esrc,
    const float* __restrict__ s, const float* __restrict__ d,
    const __half* __restrict__ h, int lane32, int base, int fl) {
  float dn = d[node];
  int j = start + (lane32 < deg ? lane32 : 0);
  int sj = esrc[j];
  float e = lrelu(s[sj] + dn);
  float ev = (lane32 < deg) ? e : -INFINITY;
  float m = ev;
  for (int o = 16; o; o >>= 1) m = fmaxf(m, __shfl_xor(m, o));
  float w = (lane32 < deg) ? __expf(e - m) : 0.f;
  float wsum = w;
  for (int o = 16; o; o >>= 1) wsum += __shfl_xor(wsum, o);
  float alpha = w / wsum;
  float2 acc = {0.f, 0.f};
  for (int t = 0; t < deg; t += 4) {
#pragma unroll
    for (int i = 0; i < 4; ++i) {
      int p = __shfl(sj, base + t + i);
      float a = __shfl(alpha, base + t + i);
      unsigned off = ((unsigned)p << 6) + fl;
      float2 hv = __half22float2(*(const __half2*)&h[off]);
      acc.x = fmaf(a, hv.x, acc.x);
      acc.y = fmaf(a, hv.y, acc.y);
    }
  }
  return acc;
}

// full-wave fallback (deg > 32): dual-edge layout; returns full sums.
__device__ float2 gat_node_full(
    int node, const int* __restrict__ rowptr, const int* __restrict__ esrc,
    const float* __restrict__ s, const float* __restrict__ d,
    const __half* __restrict__ h, int lane, int half, int fl) {
  int start = rowptr[node], end = rowptr[node + 1];
  int deg = end - start;
  float dn = d[node];
  float2 acc = {0.f, 0.f};
  if (deg <= 64) {
    int j = start + (lane < deg ? lane : 0);
    int sj = esrc[j];
    float e = lrelu(s[sj] + dn);
    float ev = (lane < deg) ? e : -INFINITY;
    float m = ev;
    for (int o = 32; o; o >>= 1) m = fmaxf(m, __shfl_xor(m, o));
    float w = (lane < deg) ? __expf(e - m) : 0.f;
    float wsum = w;
    for (int o = 32; o; o >>= 1) wsum += __shfl_xor(wsum, o);
    float alpha = w / wsum;
    for (int t = 0; t < deg; t += 8) {
#pragma unroll
      for (int i = 0; i < 4; ++i) {
        int e0 = t + 2 * i;
        int p0 = __builtin_amdgcn_readlane(sj, e0);
        int p1 = __builtin_amdgcn_readlane(sj, e0 + 1);
        float a0 = readlane_f(alpha, e0);
        float a1 = readlane_f(alpha, e0 + 1);
        int ps = half ? p1 : p0;
        float aw = half ? a1 : a0;
        unsigned off = ((unsigned)ps << 6) + fl;
        float2 hv = __half22float2(*(const __half2*)&h[off]);
        acc.x = fmaf(aw, hv.x, acc.x);
        acc.y = fmaf(aw, hv.y, acc.y);
      }
    }
  } else {
    float m = -INFINITY;
    for (int j = start + lane; j < end; j += 64)
      m = fmaxf(m, lrelu(s[esrc[j]] + dn));
    for (int o = 32; o; o >>= 1) m = fmaxf(m, __shfl_xor(m, o));
    float wsum = 0.f;
    for (int j = start + lane; j < end; j += 64)
      wsum += __expf(lrelu(s[esrc[j]] + dn) - m);
    for (int o = 32; o; o >>= 1) wsum += __shfl_xor(wsum, o);
    float inv = 1.0f / wsum;
    for (int cb = start; cb < end; cb += 64) {
      int cc = min(64, end - cb);
      int j = cb + (lane < cc ? lane : 0);
      int sj = esrc[j];
      float alpha = (lane < cc) ? __expf(lrelu(s[sj] + dn) - m) * inv : 0.f;
      for (int t = 0; t < cc; t += 8) {
#pragma unroll
        for (int i = 0; i < 4; ++i) {
          int e0 = t + 2 * i;
          int p0 = __builtin_amdgcn_readlane(sj, e0);
          int p1 = __builtin_amdgcn_readlane(sj, e0 + 1);
          float a0 = readlane_f(alpha, e0);
          float a1 = readlane_f(alpha, e0 + 1);
          int ps = half ? p1 : p0;
          float aw = half ? a1 : a0;
          unsigned off = ((unsigned)ps << 6) + fl;
          float2 hv = __half22float2(*(const __half2*)&h[off]);
          acc.x = fmaf(aw, hv.x, acc.x);
          acc.y = fmaf(aw, hv.y, acc.y);
        }
      }
    }
  }
  acc.x += __shfl_xor(acc.x, 32);
  acc.y += __shfl_xor(acc.y, 32);
  return acc;
}

__device__ __forceinline__ float2 gat_pair(
    int nA, const int* __restrict__ rowptr, const int* __restrict__ esrc,
    const float* __restrict__ s, const float* __restrict__ d,
    const __half* __restrict__ h, int lane, int half, int lane32, int fl) {
  int nB = nA + 1;
  int sA = rowptr[nA], sB = rowptr[nB], eB = rowptr[nB + 1];
  int degA = sB - sA, degB = eB - sB;
  if (degA <= 32 && degB <= 32) {
    int node = half ? nB : nA;
    int start = half ? sB : sA;
    int deg = half ? degB : degA;
    return gat_node_half(node, start, deg, esrc, s, d, h, lane32, half << 5, fl);
  }
  float2 aA = gat_node_full(nA, rowptr, esrc, s, d, h, lane, half, fl);
  float2 aB = gat_node_full(nB, rowptr, esrc, s, d, h, lane, half, fl);
  return half ? aB : aA;
}

// layer-1 aggregation: strided node PAIRS; each half writes its node's y.
__global__ __launch_bounds__(256) void gat_agg_k(
    const int* __restrict__ rowptr, const int* __restrict__ esrc,
    const float* __restrict__ s, const float* __restrict__ d,
    const __half* __restrict__ h, const float* __restrict__ bias,
    float* __restrict__ y, float* __restrict__ fsum, float* __restrict__ fsq) {
  __shared__ float lsum[HID], lsq[HID];
  int tid = threadIdx.x;
  if (tid < HID) { lsum[tid] = 0.f; lsq[tid] = 0.f; }
  __syncthreads();
  int lane = tid & 63;
  int half = lane >> 5;
  int lane32 = lane & 31;
  int fl = lane32 * 2;
  float2 bv = *(const float2*)&bias[fl];
  float2 ls = {0.f, 0.f}, lq = {0.f, 0.f};
  int wave = blockIdx.x * 4 + (tid >> 6);
  int nwaves = gridDim.x * 4;
  for (int p = wave; p < NN / 2; p += nwaves) {
    int nA = 2 * p;
    float2 acc = gat_pair(nA, rowptr, esrc, s, d, h, lane, half, lane32, fl);
    float vx = fmaxf(acc.x + bv.x, 0.f);
    float vy = fmaxf(acc.y + bv.y, 0.f);
    int node = nA + half;
    *(float2*)&y[(size_t)node * HID + fl] = make_float2(vx, vy);
    ls.x += vx; ls.y += vy;
    lq.x += vx * vx; lq.y += vy * vy;
  }
  atomicAdd(&lsum[fl + 0], ls.x);
  atomicAdd(&lsum[fl + 1], ls.y);
  atomicAdd(&lsq[fl + 0], lq.x);
  atomicAdd(&lsq[fl + 1], lq.y);
  __syncthreads();
  if (tid < HID) { atomicAdd(&fsum[tid], lsum[tid]); atomicAdd(&fsq[tid], lsq[tid]); }
}

// layer-2 aggregation + fused pooling: contiguous EVEN-sized node ranges.
__global__ __launch_bounds__(256) void gat_agg_pool_k(
    const int* __restrict__ rowptr, const int* __restrict__ esrc,
    const float* __restrict__ s, const float* __restrict__ d,
    const __half* __restrict__ h, const float* __restrict__ bias,
    const int* __restrict__ batch, float* __restrict__ pooled,
    float* __restrict__ cnt, float* __restrict__ fsum, float* __restrict__ fsq) {
  __shared__ float lsum[HID], lsq[HID];
  int tid = threadIdx.x;
  if (tid < HID) { lsum[tid] = 0.f; lsq[tid] = 0.f; }
  __syncthreads();
  int lane = tid & 63;
  int half = lane >> 5;
  int lane32 = lane & 31;
  int fl = lane32 * 2;
  float2 bv = *(const float2*)&bias[fl];
  float2 ls = {0.f, 0.f}, lq = {0.f, 0.f};
  int wave = blockIdx.x * 4 + (tid >> 6);
  int nwaves = gridDim.x * 4;
  int per = (((NN / 2) + nwaves - 1) / nwaves) * 2;
  int lo = wave * per, hi = min(lo + per, NN);
  if (lo < hi) {
    int g = batch[lo + half];
    float2 pacc = {0.f, 0.f};
    float c = 0.f;
    for (int nA = lo; nA < hi; nA += 2) {
      int myn = nA + half;
      int bg = batch[myn];
      if (bg != g) {
        atomicAdd(&pooled[g * HID + fl + 0], pacc.x);
        atomicAdd(&pooled[g * HID + fl + 1], pacc.y);
        if (lane32 == 0) atomicAdd(&cnt[g], c);
        g = bg; pacc.x = 0.f; pacc.y = 0.f; c = 0.f;
      }
      float2 acc = gat_pair(nA, rowptr, esrc, s, d, h, lane, half, lane32, fl);
      float vx = fmaxf(acc.x + bv.x, 0.f);
      float vy = fmaxf(acc.y + bv.y, 0.f);
      pacc.x += vx; pacc.y += vy; c += 1.f;
      ls.x += vx; ls.y += vy;
      lq.x += vx * vx; lq.y += vy * vy;
    }
    atomicAdd(&pooled[g * HID + fl + 0], pacc.x);
    atomicAdd(&pooled[g * HID + fl + 1], pacc.y);
    if (lane32 == 0) atomicAdd(&cnt[g], c);
  }
  atomicAdd(&lsum[fl + 0], ls.x);
  atomicAdd(&lsum[fl + 1], ls.y);
  atomicAdd(&lsq[fl + 0], lq.x);
  atomicAdd(&lsq[fl + 1], lq.y);
  __syncthreads();
  if (tid < HID) { atomicAdd(&fsum[tid], lsum[tid]); atomicAdd(&fsq[tid], lsq[tid]); }
}

// one block (64 threads) per graph: BN2 affine + mean + full MLP head
__global__ __launch_bounds__(64) void mlp_head(
    const float* __restrict__ pooled, const float* __restrict__ cnt,
    const float* __restrict__ fsum, const float* __restrict__ fsq,
    const float* __restrict__ bng, const float* __restrict__ bnb,
    const float* __restrict__ m1w, const float* __restrict__ m1b,
    const float* __restrict__ m2w, const float* __restrict__ m2b,
    const float* __restrict__ m3w, const float* __restrict__ m3b,
    const float* __restrict__ m4w, const float* __restrict__ m4b,
    float* __restrict__ out) {
  __shared__ float p[64], z1[64], z2[16], z3[8];
  int g = blockIdx.x, f = threadIdx.x;
  float m = fsum[f] * (1.0f / NN);
  float v = fsq[f] * (1.0f / NN) - m * m;
  float a = bng[f] * rsqrtf(v + BN_EPS);
  float c = bnb[f] - m * a;
  float cv = fmaxf(cnt[g], 1.0f);
  p[f] = a * pooled[g * 64 + f] / cv + c;
  __syncthreads();
  float a1 = m1b[f];
  for (int k = 0; k < 64; ++k) a1 += p[k] * m1w[k * 64 + f];
  z1[f] = fmaxf(a1, 0.f);
  __syncthreads();
  if (f < 16) {
    float a2 = m2b[f];
    for (int k = 0; k < 64; ++k) a2 += z1[k] * m2w[k * 16 + f];
    z2[f] = fmaxf(a2, 0.f);
  }
  __syncthreads();
  if (f < 8) {
    float a3 = m3b[f];
    for (int k = 0; k < 16; ++k) a3 += z2[k] * m3w[k * 8 + f];
    z3[f] = fmaxf(a3, 0.f);
  }
  __syncthreads();
  if (f < 10) {
    float a4 = m4b[f];
    for (int k = 0; k < 8; ++k) a4 += z3[k] * m4w[k * 10 + f];
    out[g * 10 + f] = a4;
  }
}

extern "C" void kernel_launch(void* const* d_in, const int* in_sizes, int n_in,
                              void* d_out, int out_size, void* d_ws, size_t ws_size,
                              hipStream_t stream) {
  const float* x   = (const float*)d_in[0];
  const int*   ei  = (const int*)d_in[1];
  const int*   bat = (const int*)d_in[2];
  const float* W1  = (const float*)d_in[3];
  const float* as1 = (const float*)d_in[4];
  const float* ad1 = (const float*)d_in[5];
  const float* b1  = (const float*)d_in[6];
  const float* W2  = (const float*)d_in[7];
  const float* as2 = (const float*)d_in[8];
  const float* ad2 = (const float*)d_in[9];
  const float* b2  = (const float*)d_in[10];
  const float* bng = (const float*)d_in[11];
  const float* bnb = (const float*)d_in[12];
  const float* m1w = (const float*)d_in[13];
  const float* m1b = (const float*)d_in[14];
  const float* m2w = (const float*)d_in[15];
  const float* m2b = (const float*)d_in[16];
  const float* m3w = (const float*)d_in[17];
  const float* m3b = (const float*)d_in[18];
  const float* m4w = (const float*)d_in[19];
  const float* m4b = (const float*)d_in[20];
  float* out = (float*)d_out;

  float* ws = (float*)d_ws;
  size_t off = 0;
  __half* hbuf = (__half*)(ws + off); off += (size_t)NN * HID / 2;  // fp16 h
  float* ybuf = ws + off; off += (size_t)NN * HID;   // layer-1 output y (fp32)
  float* sbuf = ws + off; off += NN;                 // alpha_s
  float* dbuf = ws + off; off += NN;                 // alpha_d
  int* rowptr = (int*)(ws + off); off += NN + 1;
  int* esrc   = (int*)(ws + off); off += ET;         // CSR: src per dst-sorted edge
  int* bukcur = (int*)(ws + off); off += NBUK;
  float* fsum1 = ws + off; off += HID;
  float* fsq1  = ws + off; off += HID;
  float* fsum2 = ws + off; off += HID;
  float* fsq2  = ws + off; off += HID;
  float* pooled = ws + off; off += (size_t)NG * HID; // raw per-graph sums
  float* cnt  = ws + off; off += NG;
  // 16MB staging aliases ybuf (stage dead before agg1 first writes ybuf)
  int2* stage = (int2*)ybuf;

  dim3 b256(256);
  const int aggGrid = 3125;   // 12500 waves: exactly 4 pairs / 8 nodes each
  const size_t fusedLds = (size_t)(INF_ * HID + HID) * sizeof(float); // 33KB

  // ---------- init ----------
  init_k<<<(NG * HID + 255) / 256, b256, 0, stream>>>(bukcur, rowptr, fsum1,
                                                      fsq1, fsum2, fsq2,
                                                      pooled, cnt);
  // ---------- bucket partition || layer-1 GEMM (independent) ----------
  p1_gemm1_k<<<P1_GRID + GEMM_GRID, b256, fusedLds, stream>>>(
      ei, bukcur, stage, x, W1, as1, ad1, hbuf, sbuf, dbuf);
  // ---------- CSR finalize (per-bucket local sort; inline bucket base) ----
  part2_k<<<NBUK, b256, 0, stream>>>(stage, bukcur, rowptr, esrc);

  // ---------- layer 1 aggregation ----------
  gat_agg_k<<<aggGrid, b256, 0, stream>>>(rowptr, esrc, sbuf, dbuf, hbuf, b1,
                                          ybuf, fsum1, fsq1);

  // ---------- layer 2 (BN1 inline in gemm; pooling fused into agg) ----------
  gemm_att<HID, true><<<GEMM_GRID, b256, 0, stream>>>(
      ybuf, fsum1, fsq1, bng, bnb, W2, as2, ad2, hbuf, sbuf, dbuf);
  gat_agg_pool_k<<<aggGrid, b256, 0, stream>>>(rowptr, esrc, sbuf, dbuf, hbuf,
                                               b2, bat, pooled, cnt, fsum2, fsq2);

  // ---------- MLP head (BN2 inline) ----------
  mlp_head<<<NG, 64, 0, stream>>>(pooled, cnt, fsum2, fsq2, bng, bnb,
                                  m1w, m1b, m2w, m2b, m3w, m3b, m4w, m4b, out);
}

// Round 18
// 376.778 us; speedup vs baseline: 1.1140x; 1.1140x over previous
//
#include <hip/hip_runtime.h>
#include <hip/hip_fp16.h>

// Problem constants (match reference)
#define NN   100000              // nodes
#define NE   1600000             // edges before self loops
#define ET   (NE + NN)           // edges incl. self loops
#define INF_ 128                 // input features
#define HID  64                  // hidden
#define NG   256                 // graphs
#define BN_EPS 1e-5f
#define NEG  0.2f

// bucket partition geometry (CSR fill)
#define BSPAN_LOG 8
#define BSPAN     (1 << BSPAN_LOG)                 // 256 dst nodes per bucket
#define NBUK      ((NN + BSPAN - 1) / BSPAN)       // 391
#define BUKCAP    5120                             // >= mu+12sigma of bucket load
#define P1_EPT    16
#define P1_CHUNK  (256 * P1_EPT)                   // 4096 edges per block

__device__ __forceinline__ float lrelu(float v) { return v > 0.f ? v : NEG * v; }

__device__ __forceinline__ float readlane_f(float v, int l) {
  return __int_as_float(__builtin_amdgcn_readlane(__float_as_int(v), l));
}

// ---------------- unified init ----------------
__global__ __launch_bounds__(256) void init_k(
    int* __restrict__ bukcur,
    float* __restrict__ fsum1, float* __restrict__ fsq1,
    float* __restrict__ fsum2, float* __restrict__ fsq2,
    float* __restrict__ pooled, float* __restrict__ cnt) {
  int i = blockIdx.x * 256 + threadIdx.x;
  if (i < NBUK) bukcur[i] = i * BUKCAP;
  if (i < HID) { fsum1[i] = 0.f; fsq1[i] = 0.f; fsum2[i] = 0.f; fsq2[i] = 0.f; }
  if (i < NG * HID) pooled[i] = 0.f;
  if (i < NG) cnt[i] = 0.f;
}

// ---------------- CSR build (edges sorted by dst) ----------------
__global__ __launch_bounds__(256) void part1_k(const int* __restrict__ ei,
                                               int* __restrict__ bukcur,
                                               int2* __restrict__ stage) {
  __shared__ int hist[NBUK];
  __shared__ int base[NBUK];
  int t = threadIdx.x;
  for (int b = t; b < NBUK; b += 256) hist[b] = 0;
  __syncthreads();
  int chunk = blockIdx.x * P1_CHUNK;
  int myb[P1_EPT], myr[P1_EPT], mys[P1_EPT], myd[P1_EPT];
#pragma unroll
  for (int it = 0; it < P1_EPT; ++it) {
    int i = chunk + it * 256 + t;
    bool v = i < ET;
    int src = 0, dst = 0;
    if (v) {
      src = i < NE ? ei[i] : i - NE;
      dst = i < NE ? ei[NE + i] : i - NE;
    }
    myb[it] = v ? (dst >> BSPAN_LOG) : -1;
    mys[it] = src;
    myd[it] = dst;
    myr[it] = v ? atomicAdd(&hist[dst >> BSPAN_LOG], 1) : 0;
  }
  __syncthreads();
  for (int b = t; b < NBUK; b += 256)
    base[b] = hist[b] ? atomicAdd(&bukcur[b], hist[b]) : 0;
  __syncthreads();
#pragma unroll
  for (int it = 0; it < P1_EPT; ++it)
    if (myb[it] >= 0)
      stage[base[myb[it]] + myr[it]] = make_int2(mys[it], myd[it]);
}

__global__ __launch_bounds__(512) void bukscan_k(const int* __restrict__ bukcur,
                                                 int* __restrict__ bukbase,
                                                 int* __restrict__ rowptr) {
  __shared__ int sh[512];
  int t = threadIdx.x;
  int c = (t < NBUK) ? (bukcur[t] - t * BUKCAP) : 0;
  sh[t] = c;
  __syncthreads();
  for (int off = 1; off < 512; off <<= 1) {
    int add = (t >= off) ? sh[t - off] : 0;
    __syncthreads();
    sh[t] += add;
    __syncthreads();
  }
  if (t < NBUK) bukbase[t] = sh[t] - c;
  if (t == 0) rowptr[NN] = ET;
}

__global__ __launch_bounds__(256) void part2_k(const int2* __restrict__ stage,
                                               const int* __restrict__ bukcur,
                                               const int* __restrict__ bukbase,
                                               int* __restrict__ rowptr,
                                               int* __restrict__ esrc) {
  __shared__ int lcnt[BSPAN];
  __shared__ int lscan[BSPAN];
  int b = blockIdx.x;
  int node0 = b << BSPAN_LOG;
  int t = threadIdx.x;
  lcnt[t] = 0;
  __syncthreads();
  int s = b * BUKCAP, e = bukcur[b];
  for (int i = s + t; i < e; i += 256)
    atomicAdd(&lcnt[stage[i].y - node0], 1);
  __syncthreads();
  int v = lcnt[t];
  lscan[t] = v;
  __syncthreads();
  for (int off = 1; off < 256; off <<= 1) {
    int add = (t >= off) ? lscan[t - off] : 0;
    __syncthreads();
    lscan[t] += add;
    __syncthreads();
  }
  int excl = bukbase[b] + lscan[t] - v;
  if (node0 + t < NN) rowptr[node0 + t] = excl;
  lcnt[t] = excl;
  __syncthreads();
  for (int i = s + t; i < e; i += 256) {
    int2 p = stage[i];
    int pos = atomicAdd(&lcnt[p.y - node0], 1);
    esrc[pos] = p.x;
  }
}

// ---------------- GEMM + attention logits (v4 + fp16 h) ----------------
template <int K, bool STATS>
__global__ __launch_bounds__(256) void gemm_att(
    const float* __restrict__ x,
    const float* __restrict__ fsum, const float* __restrict__ fsq,
    const float* __restrict__ bng, const float* __restrict__ bnb,
    const float* __restrict__ W,
    const float* __restrict__ a_s, const float* __restrict__ a_d,
    __half* __restrict__ h, float* __restrict__ sv_out, float* __restrict__ dv_out) {
  __shared__ float Wl[K * HID];          // [k][f]: lane reads stride-1
  __shared__ float cvec[HID];
  __shared__ float scl[HID], shf[HID];
  int tid = threadIdx.x;
  if (tid < HID) {
    cvec[tid] = 0.f;
    if (STATS) {
      float m = fsum[tid] * (1.0f / NN);
      float v = fsq[tid] * (1.0f / NN) - m * m;
      float a = bng[tid] * rsqrtf(v + BN_EPS);
      scl[tid] = a;
      shf[tid] = bnb[tid] - m * a;
    }
  }
  __syncthreads();
  if (STATS) {
    float clocal = 0.f;
    for (int i = tid; i < K * HID; i += 256) {
      int k = i >> 6;
      float w = W[i];
      clocal += shf[k] * w;
      Wl[i] = w * scl[k];
    }
    atomicAdd(&cvec[tid & 63], clocal);
  } else {
    for (int i = tid; i < K * HID; i += 256) Wl[i] = W[i];
  }
  __syncthreads();

  int lane = tid & 63;
  int wid = tid >> 6;
  int row0 = blockIdx.x * 16 + wid * 4;
  int ur = __builtin_amdgcn_readfirstlane(row0);
  const float* xr0 = x + (size_t)ur * K;   // uniform -> scalar loads
  const float* xr1 = xr0 + K;
  const float* xr2 = xr0 + 2 * K;
  const float* xr3 = xr0 + 3 * K;
  float cv = cvec[lane];
  float a0 = cv, a1 = cv, a2 = cv, a3 = cv;
#pragma unroll 4
  for (int k = 0; k < K; k += 4) {
    float4 v0 = *(const float4*)(xr0 + k);
    float4 v1 = *(const float4*)(xr1 + k);
    float4 v2 = *(const float4*)(xr2 + k);
    float4 v3 = *(const float4*)(xr3 + k);
    float w0 = Wl[(k + 0) * HID + lane];
    float w1 = Wl[(k + 1) * HID + lane];
    float w2 = Wl[(k + 2) * HID + lane];
    float w3 = Wl[(k + 3) * HID + lane];
    a0 = fmaf(v0.x, w0, a0); a0 = fmaf(v0.y, w1, a0);
    a0 = fmaf(v0.z, w2, a0); a0 = fmaf(v0.w, w3, a0);
    a1 = fmaf(v1.x, w0, a1); a1 = fmaf(v1.y, w1, a1);
    a1 = fmaf(v1.z, w2, a1); a1 = fmaf(v1.w, w3, a1);
    a2 = fmaf(v2.x, w0, a2); a2 = fmaf(v2.y, w1, a2);
    a2 = fmaf(v2.z, w2, a2); a2 = fmaf(v2.w, w3, a2);
    a3 = fmaf(v3.x, w0, a3); a3 = fmaf(v3.y, w1, a3);
    a3 = fmaf(v3.z, w2, a3); a3 = fmaf(v3.w, w3, a3);
  }

  float asl = a_s[lane], adl = a_d[lane];
  h[(size_t)(row0 + 0) * HID + lane] = __float2half(a0);
  h[(size_t)(row0 + 1) * HID + lane] = __float2half(a1);
  h[(size_t)(row0 + 2) * HID + lane] = __float2half(a2);
  h[(size_t)(row0 + 3) * HID + lane] = __float2half(a3);
  float s0 = a0 * asl, d0 = a0 * adl;
  float s1 = a1 * asl, d1 = a1 * adl;
  float s2 = a2 * asl, d2 = a2 * adl;
  float s3 = a3 * asl, d3 = a3 * adl;
  for (int o = 32; o; o >>= 1) {
    s0 += __shfl_xor(s0, o); d0 += __shfl_xor(d0, o);
    s1 += __shfl_xor(s1, o); d1 += __shfl_xor(d1, o);
    s2 += __shfl_xor(s2, o); d2 += __shfl_xor(d2, o);
    s3 += __shfl_xor(s3, o); d3 += __shfl_xor(d3, o);
  }
  if (lane == 0) {
    sv_out[row0 + 0] = s0; dv_out[row0 + 0] = d0;
    sv_out[row0 + 1] = s1; dv_out[row0 + 1] = d1;
    sv_out[row0 + 2] = s2; dv_out[row0 + 2] = d2;
    sv_out[row0 + 3] = s3; dv_out[row0 + 3] = d3;
  }
}

// ---------------- half-wave node processing (deg <= 32) ----------------
// 32 lanes own one node: softmax at width 32, gather half2/lane, 4-deep.
// R15: agg invariant to traffic (fp16 halved FETCH, dur unchanged);
// R16: invariant to VALU (Busy 40->14%) and chains (x2) -- fixed per-
// gather-stream issue cost. ~122us/layer = empirical floor.
__device__ __forceinline__ float2 gat_node_half(
    int node, int start, int deg, const int* __restrict__ esrc,
    const float* __restrict__ s, const float* __restrict__ d,
    const __half* __restrict__ h, int lane32, int base, int fl) {
  float dn = d[node];
  int j = start + (lane32 < deg ? lane32 : 0);
  int sj = esrc[j];
  float e = lrelu(s[sj] + dn);
  float ev = (lane32 < deg) ? e : -INFINITY;
  float m = ev;
  for (int o = 16; o; o >>= 1) m = fmaxf(m, __shfl_xor(m, o));
  float w = (lane32 < deg) ? __expf(e - m) : 0.f;
  float wsum = w;
  for (int o = 16; o; o >>= 1) wsum += __shfl_xor(wsum, o);
  float alpha = w / wsum;
  float2 acc = {0.f, 0.f};
  for (int t = 0; t < deg; t += 4) {
#pragma unroll
    for (int i = 0; i < 4; ++i) {
      int p = __shfl(sj, base + t + i);
      float a = __shfl(alpha, base + t + i);
      unsigned off = ((unsigned)p << 6) + fl;
      float2 hv = __half22float2(*(const __half2*)&h[off]);
      acc.x = fmaf(a, hv.x, acc.x);
      acc.y = fmaf(a, hv.y, acc.y);
    }
  }
  return acc;
}

// full-wave fallback (deg > 32): dual-edge layout; returns full sums.
__device__ float2 gat_node_full(
    int node, const int* __restrict__ rowptr, const int* __restrict__ esrc,
    const float* __restrict__ s, const float* __restrict__ d,
    const __half* __restrict__ h, int lane, int half, int fl) {
  int start = rowptr[node], end = rowptr[node + 1];
  int deg = end - start;
  float dn = d[node];
  float2 acc = {0.f, 0.f};
  if (deg <= 64) {
    int j = start + (lane < deg ? lane : 0);
    int sj = esrc[j];
    float e = lrelu(s[sj] + dn);
    float ev = (lane < deg) ? e : -INFINITY;
    float m = ev;
    for (int o = 32; o; o >>= 1) m = fmaxf(m, __shfl_xor(m, o));
    float w = (lane < deg) ? __expf(e - m) : 0.f;
    float wsum = w;
    for (int o = 32; o; o >>= 1) wsum += __shfl_xor(wsum, o);
    float alpha = w / wsum;
    for (int t = 0; t < deg; t += 8) {
#pragma unroll
      for (int i = 0; i < 4; ++i) {
        int e0 = t + 2 * i;
        int p0 = __builtin_amdgcn_readlane(sj, e0);
        int p1 = __builtin_amdgcn_readlane(sj, e0 + 1);
        float a0 = readlane_f(alpha, e0);
        float a1 = readlane_f(alpha, e0 + 1);
        int ps = half ? p1 : p0;
        float aw = half ? a1 : a0;
        unsigned off = ((unsigned)ps << 6) + fl;
        float2 hv = __half22float2(*(const __half2*)&h[off]);
        acc.x = fmaf(aw, hv.x, acc.x);
        acc.y = fmaf(aw, hv.y, acc.y);
      }
    }
  } else {
    float m = -INFINITY;
    for (int j = start + lane; j < end; j += 64)
      m = fmaxf(m, lrelu(s[esrc[j]] + dn));
    for (int o = 32; o; o >>= 1) m = fmaxf(m, __shfl_xor(m, o));
    float wsum = 0.f;
    for (int j = start + lane; j < end; j += 64)
      wsum += __expf(lrelu(s[esrc[j]] + dn) - m);
    for (int o = 32; o; o >>= 1) wsum += __shfl_xor(wsum, o);
    float inv = 1.0f / wsum;
    for (int cb = start; cb < end; cb += 64) {
      int cc = min(64, end - cb);
      int j = cb + (lane < cc ? lane : 0);
      int sj = esrc[j];
      float alpha = (lane < cc) ? __expf(lrelu(s[sj] + dn) - m) * inv : 0.f;
      for (int t = 0; t < cc; t += 8) {
#pragma unroll
        for (int i = 0; i < 4; ++i) {
          int e0 = t + 2 * i;
          int p0 = __builtin_amdgcn_readlane(sj, e0);
          int p1 = __builtin_amdgcn_readlane(sj, e0 + 1);
          float a0 = readlane_f(alpha, e0);
          float a1 = readlane_f(alpha, e0 + 1);
          int ps = half ? p1 : p0;
          float aw = half ? a1 : a0;
          unsigned off = ((unsigned)ps << 6) + fl;
          float2 hv = __half22float2(*(const __half2*)&h[off]);
          acc.x = fmaf(aw, hv.x, acc.x);
          acc.y = fmaf(aw, hv.y, acc.y);
        }
      }
    }
  }
  acc.x += __shfl_xor(acc.x, 32);
  acc.y += __shfl_xor(acc.y, 32);
  return acc;
}

__device__ __forceinline__ float2 gat_pair(
    int nA, const int* __restrict__ rowptr, const int* __restrict__ esrc,
    const float* __restrict__ s, const float* __restrict__ d,
    const __half* __restrict__ h, int lane, int half, int lane32, int fl) {
  int nB = nA + 1;
  int sA = rowptr[nA], sB = rowptr[nB], eB = rowptr[nB + 1];
  int degA = sB - sA, degB = eB - sB;
  if (degA <= 32 && degB <= 32) {
    int node = half ? nB : nA;
    int start = half ? sB : sA;
    int deg = half ? degB : degA;
    return gat_node_half(node, start, deg, esrc, s, d, h, lane32, half << 5, fl);
  }
  float2 aA = gat_node_full(nA, rowptr, esrc, s, d, h, lane, half, fl);
  float2 aB = gat_node_full(nB, rowptr, esrc, s, d, h, lane, half, fl);
  return half ? aB : aA;
}

// layer-1 aggregation: strided node PAIRS; each half writes its node's y.
__global__ __launch_bounds__(256) void gat_agg_k(
    const int* __restrict__ rowptr, const int* __restrict__ esrc,
    const float* __restrict__ s, const float* __restrict__ d,
    const __half* __restrict__ h, const float* __restrict__ bias,
    float* __restrict__ y, float* __restrict__ fsum, float* __restrict__ fsq) {
  __shared__ float lsum[HID], lsq[HID];
  int tid = threadIdx.x;
  if (tid < HID) { lsum[tid] = 0.f; lsq[tid] = 0.f; }
  __syncthreads();
  int lane = tid & 63;
  int half = lane >> 5;
  int lane32 = lane & 31;
  int fl = lane32 * 2;
  float2 bv = *(const float2*)&bias[fl];
  float2 ls = {0.f, 0.f}, lq = {0.f, 0.f};
  int wave = blockIdx.x * 4 + (tid >> 6);
  int nwaves = gridDim.x * 4;
  for (int p = wave; p < NN / 2; p += nwaves) {
    int nA = 2 * p;
    float2 acc = gat_pair(nA, rowptr, esrc, s, d, h, lane, half, lane32, fl);
    float vx = fmaxf(acc.x + bv.x, 0.f);
    float vy = fmaxf(acc.y + bv.y, 0.f);
    int node = nA + half;
    *(float2*)&y[(size_t)node * HID + fl] = make_float2(vx, vy);
    ls.x += vx; ls.y += vy;
    lq.x += vx * vx; lq.y += vy * vy;
  }
  atomicAdd(&lsum[fl + 0], ls.x);
  atomicAdd(&lsum[fl + 1], ls.y);
  atomicAdd(&lsq[fl + 0], lq.x);
  atomicAdd(&lsq[fl + 1], lq.y);
  __syncthreads();
  if (tid < HID) { atomicAdd(&fsum[tid], lsum[tid]); atomicAdd(&fsq[tid], lsq[tid]); }
}

// layer-2 aggregation + fused pooling: contiguous EVEN-sized node ranges.
// R17 lesson: pool-flush atomics scale with wave count -- keep 2048 blocks
// (8192 waves, ~14-node ranges), NOT 3125 (8-node ranges regressed +26us).
__global__ __launch_bounds__(256) void gat_agg_pool_k(
    const int* __restrict__ rowptr, const int* __restrict__ esrc,
    const float* __restrict__ s, const float* __restrict__ d,
    const __half* __restrict__ h, const float* __restrict__ bias,
    const int* __restrict__ batch, float* __restrict__ pooled,
    float* __restrict__ cnt, float* __restrict__ fsum, float* __restrict__ fsq) {
  __shared__ float lsum[HID], lsq[HID];
  int tid = threadIdx.x;
  if (tid < HID) { lsum[tid] = 0.f; lsq[tid] = 0.f; }
  __syncthreads();
  int lane = tid & 63;
  int half = lane >> 5;
  int lane32 = lane & 31;
  int fl = lane32 * 2;
  float2 bv = *(const float2*)&bias[fl];
  float2 ls = {0.f, 0.f}, lq = {0.f, 0.f};
  int wave = blockIdx.x * 4 + (tid >> 6);
  int nwaves = gridDim.x * 4;
  int per = (((NN / 2) + nwaves - 1) / nwaves) * 2;   // even range size
  int lo = wave * per, hi = min(lo + per, NN);
  if (lo < hi) {
    int g = batch[lo + half];
    float2 pacc = {0.f, 0.f};
    float c = 0.f;
    for (int nA = lo; nA < hi; nA += 2) {
      int myn = nA + half;
      int bg = batch[myn];
      if (bg != g) {
        atomicAdd(&pooled[g * HID + fl + 0], pacc.x);
        atomicAdd(&pooled[g * HID + fl + 1], pacc.y);
        if (lane32 == 0) atomicAdd(&cnt[g], c);
        g = bg; pacc.x = 0.f; pacc.y = 0.f; c = 0.f;
      }
      float2 acc = gat_pair(nA, rowptr, esrc, s, d, h, lane, half, lane32, fl);
      float vx = fmaxf(acc.x + bv.x, 0.f);
      float vy = fmaxf(acc.y + bv.y, 0.f);
      pacc.x += vx; pacc.y += vy; c += 1.f;
      ls.x += vx; ls.y += vy;
      lq.x += vx * vx; lq.y += vy * vy;
    }
    atomicAdd(&pooled[g * HID + fl + 0], pacc.x);
    atomicAdd(&pooled[g * HID + fl + 1], pacc.y);
    if (lane32 == 0) atomicAdd(&cnt[g], c);
  }
  atomicAdd(&lsum[fl + 0], ls.x);
  atomicAdd(&lsum[fl + 1], ls.y);
  atomicAdd(&lsq[fl + 0], lq.x);
  atomicAdd(&lsq[fl + 1], lq.y);
  __syncthreads();
  if (tid < HID) { atomicAdd(&fsum[tid], lsum[tid]); atomicAdd(&fsq[tid], lsq[tid]); }
}

// one block (64 threads) per graph: BN2 affine + mean + full MLP head
__global__ __launch_bounds__(64) void mlp_head(
    const float* __restrict__ pooled, const float* __restrict__ cnt,
    const float* __restrict__ fsum, const float* __restrict__ fsq,
    const float* __restrict__ bng, const float* __restrict__ bnb,
    const float* __restrict__ m1w, const float* __restrict__ m1b,
    const float* __restrict__ m2w, const float* __restrict__ m2b,
    const float* __restrict__ m3w, const float* __restrict__ m3b,
    const float* __restrict__ m4w, const float* __restrict__ m4b,
    float* __restrict__ out) {
  __shared__ float p[64], z1[64], z2[16], z3[8];
  int g = blockIdx.x, f = threadIdx.x;
  float m = fsum[f] * (1.0f / NN);
  float v = fsq[f] * (1.0f / NN) - m * m;
  float a = bng[f] * rsqrtf(v + BN_EPS);
  float c = bnb[f] - m * a;
  float cv = fmaxf(cnt[g], 1.0f);
  p[f] = a * pooled[g * 64 + f] / cv + c;
  __syncthreads();
  float a1 = m1b[f];
  for (int k = 0; k < 64; ++k) a1 += p[k] * m1w[k * 64 + f];
  z1[f] = fmaxf(a1, 0.f);
  __syncthreads();
  if (f < 16) {
    float a2 = m2b[f];
    for (int k = 0; k < 64; ++k) a2 += z1[k] * m2w[k * 16 + f];
    z2[f] = fmaxf(a2, 0.f);
  }
  __syncthreads();
  if (f < 8) {
    float a3 = m3b[f];
    for (int k = 0; k < 16; ++k) a3 += z2[k] * m3w[k * 8 + f];
    z3[f] = fmaxf(a3, 0.f);
  }
  __syncthreads();
  if (f < 10) {
    float a4 = m4b[f];
    for (int k = 0; k < 8; ++k) a4 += z3[k] * m4w[k * 10 + f];
    out[g * 10 + f] = a4;
  }
}

extern "C" void kernel_launch(void* const* d_in, const int* in_sizes, int n_in,
                              void* d_out, int out_size, void* d_ws, size_t ws_size,
                              hipStream_t stream) {
  const float* x   = (const float*)d_in[0];
  const int*   ei  = (const int*)d_in[1];
  const int*   bat = (const int*)d_in[2];
  const float* W1  = (const float*)d_in[3];
  const float* as1 = (const float*)d_in[4];
  const float* ad1 = (const float*)d_in[5];
  const float* b1  = (const float*)d_in[6];
  const float* W2  = (const float*)d_in[7];
  const float* as2 = (const float*)d_in[8];
  const float* ad2 = (const float*)d_in[9];
  const float* b2  = (const float*)d_in[10];
  const float* bng = (const float*)d_in[11];
  const float* bnb = (const float*)d_in[12];
  const float* m1w = (const float*)d_in[13];
  const float* m1b = (const float*)d_in[14];
  const float* m2w = (const float*)d_in[15];
  const float* m2b = (const float*)d_in[16];
  const float* m3w = (const float*)d_in[17];
  const float* m3b = (const float*)d_in[18];
  const float* m4w = (const float*)d_in[19];
  const float* m4b = (const float*)d_in[20];
  float* out = (float*)d_out;

  float* ws = (float*)d_ws;
  size_t off = 0;
  __half* hbuf = (__half*)(ws + off); off += (size_t)NN * HID / 2;  // fp16 h
  float* ybuf = ws + off; off += (size_t)NN * HID;   // layer-1 output y (fp32)
  float* sbuf = ws + off; off += NN;                 // alpha_s
  float* dbuf = ws + off; off += NN;                 // alpha_d
  int* rowptr = (int*)(ws + off); off += NN + 1;
  int* esrc   = (int*)(ws + off); off += ET;         // CSR: src per dst-sorted edge
  int* bukcur = (int*)(ws + off); off += NBUK;
  int* bukbase = (int*)(ws + off); off += NBUK;
  float* fsum1 = ws + off; off += HID;
  float* fsq1  = ws + off; off += HID;
  float* fsum2 = ws + off; off += HID;
  float* fsq2  = ws + off; off += HID;
  float* pooled = ws + off; off += (size_t)NG * HID; // raw per-graph sums
  float* cnt  = ws + off; off += NG;
  // 16MB staging aliases ybuf (stage dead before agg1 first writes ybuf)
  int2* stage = (int2*)ybuf;

  dim3 b256(256);
  const int gemmGrid = NN / 16;                      // 6250, exact
  const int p1Grid = (ET + P1_CHUNK - 1) / P1_CHUNK; // 416
  const int aggGrid = 2048;

  // ---------- CSR build (shared by both layers) ----------
  init_k<<<(NG * HID + 255) / 256, b256, 0, stream>>>(bukcur, fsum1, fsq1,
                                                      fsum2, fsq2, pooled, cnt);
  part1_k<<<p1Grid, b256, 0, stream>>>(ei, bukcur, stage);
  bukscan_k<<<1, 512, 0, stream>>>(bukcur, bukbase, rowptr);
  part2_k<<<NBUK, b256, 0, stream>>>(stage, bukcur, bukbase, rowptr, esrc);

  // ---------- layer 1 ----------
  gemm_att<INF_, false><<<gemmGrid, b256, 0, stream>>>(
      x, nullptr, nullptr, nullptr, nullptr, W1, as1, ad1, hbuf, sbuf, dbuf);
  gat_agg_k<<<aggGrid, b256, 0, stream>>>(rowptr, esrc, sbuf, dbuf, hbuf, b1,
                                          ybuf, fsum1, fsq1);

  // ---------- layer 2 (BN1 inline in gemm; pooling fused into agg) ----------
  gemm_att<HID, true><<<gemmGrid, b256, 0, stream>>>(
      ybuf, fsum1, fsq1, bng, bnb, W2, as2, ad2, hbuf, sbuf, dbuf);
  gat_agg_pool_k<<<aggGrid, b256, 0, stream>>>(rowptr, esrc, sbuf, dbuf, hbuf,
                                               b2, bat, pooled, cnt, fsum2, fsq2);

  // ---------- MLP head (BN2 inline) ----------
  mlp_head<<<NG, 64, 0, stream>>>(pooled, cnt, fsum2, fsq2, bng, bnb,
                                  m1w, m1b, m2w, m2b, m3w, m3b, m4w, m4b, out);
}